// Round 3
// baseline (588.483 us; speedup 1.0000x reference)
//
#include <hip/hip_runtime.h>
#include <math.h>

// NSLoss: N=16384 pairs, D=128, NUM_SAMPLED=10, weights table 1e6 x 128 f32.
// loss = -(1/N) * sum_i [ log_sigmoid(<emb_i, W[label_i]>)
//                         + sum_k log_sigmoid(-<emb_i, W[negs_ik]>) ]
//
// Stage 1: 2 pairs per wave, 8 per block (grid 2048). Lane l holds float2 of
// each 128-wide row; all 22 weight-row gathers for both pairs issued before
// any reduction (max memory-level parallelism). Butterfly shuffle reductions,
// one partial per block to d_ws. Stage 2: single block sums 2048 partials,
// writes -sum/N.
//
// R2 evidence: timed iteration is dominated by harness reset dispatches
// (2.048 GB fillBuffer @ ~315 us, 81% HBM peak); our kernels are ~20 us.

#define NPAIRS 16384
#define DIM 128
#define NSAMP 10
#define PAIRS_PER_WAVE 2
#define PAIRS_PER_BLOCK 8
#define NBLOCKS (NPAIRS / PAIRS_PER_BLOCK)   // 2048

__device__ __forceinline__ float log_sigmoid(float x) {
    // stable: min(x,0) - log1p(exp(-|x|))
    return fminf(x, 0.0f) - log1pf(__expf(-fabsf(x)));
}

__global__ __launch_bounds__(256) void nsloss_partial_kernel(
    const float* __restrict__ emb,      // [N, 128]
    const float* __restrict__ weights,  // [1e6, 128]
    const int*   __restrict__ label,    // [N]
    const int*   __restrict__ negs,     // [N, 10]
    float* __restrict__ partials)       // [NBLOCKS]
{
    const int wave = threadIdx.x >> 6;                       // 0..3
    const int lane = threadIdx.x & 63;
    const int i0 = blockIdx.x * PAIRS_PER_BLOCK + wave * PAIRS_PER_WAVE;

    // emb fragments for both pairs (coalesced dwordx2 each)
    float2 e[PAIRS_PER_WAVE];
    // row indices for both pairs (wave-uniform values)
    int idx[PAIRS_PER_WAVE][NSAMP + 1];
#pragma unroll
    for (int p = 0; p < PAIRS_PER_WAVE; ++p) {
        const int i = i0 + p;
        e[p] = *(const float2*)(emb + (size_t)i * DIM + 2 * lane);
        idx[p][0] = label[i];
#pragma unroll
        for (int k = 0; k < NSAMP; ++k) idx[p][k + 1] = negs[i * NSAMP + k];
    }

    // issue all 22 row loads before any reduction (latency overlap)
    float2 w[PAIRS_PER_WAVE][NSAMP + 1];
#pragma unroll
    for (int p = 0; p < PAIRS_PER_WAVE; ++p)
#pragma unroll
        for (int k = 0; k < NSAMP + 1; ++k)
            w[p][k] = *(const float2*)(weights + (size_t)idx[p][k] * DIM + 2 * lane);

    float loss = 0.0f;
#pragma unroll
    for (int p = 0; p < PAIRS_PER_WAVE; ++p)
#pragma unroll
        for (int k = 0; k < NSAMP + 1; ++k) {
            float s = e[p].x * w[p][k].x + e[p].y * w[p][k].y;
#pragma unroll
            for (int off = 32; off >= 1; off >>= 1)
                s += __shfl_xor(s, off, 64);
            loss += log_sigmoid(k == 0 ? s : -s);
        }

    __shared__ float part[4];
    if (lane == 0) part[wave] = loss;
    __syncthreads();
    if (threadIdx.x == 0)
        partials[blockIdx.x] = (part[0] + part[1]) + (part[2] + part[3]);
}

__global__ __launch_bounds__(256) void nsloss_reduce_kernel(
    const float* __restrict__ partials,  // [NBLOCKS]
    float* __restrict__ out)             // [1]
{
    const int t = threadIdx.x;
    float s = 0.0f;
#pragma unroll
    for (int j = 0; j < NBLOCKS / 256; ++j)   // 8 coalesced passes
        s += partials[j * 256 + t];
#pragma unroll
    for (int off = 32; off >= 1; off >>= 1)
        s += __shfl_xor(s, off, 64);

    __shared__ float part[4];
    if ((t & 63) == 0) part[t >> 6] = s;
    __syncthreads();
    if (t == 0)
        out[0] = ((part[0] + part[1]) + (part[2] + part[3])) * (-1.0f / (float)NPAIRS);
}

extern "C" void kernel_launch(void* const* d_in, const int* in_sizes, int n_in,
                              void* d_out, int out_size, void* d_ws, size_t ws_size,
                              hipStream_t stream) {
    // inputs (setup_inputs order): y_hat[N] (unused), emb[N*128], weights[1e6*128],
    // label[N] (int), negs[N*10] (int)
    const float* emb     = (const float*)d_in[1];
    const float* weights = (const float*)d_in[2];
    const int*   label   = (const int*)d_in[3];
    const int*   negs    = (const int*)d_in[4];
    float* out      = (float*)d_out;
    float* partials = (float*)d_ws;   // 2048 floats, fully overwritten each call

    nsloss_partial_kernel<<<NBLOCKS, 256, 0, stream>>>(emb, weights, label, negs, partials);
    nsloss_reduce_kernel<<<1, 256, 0, stream>>>(partials, out);
}